// Round 8
// baseline (91.514 us; speedup 1.0000x reference)
//
#include <hip/hip_runtime.h>
#include <stdint.h>

#define IN_F 4096
#define OUT_F 11008
#define M_ROWS 256
#define RANK 16
#define NWORDS (IN_F / 16)   // 256 packed words per output row

#define BM 64
#define BN 32
#define BK 64
#define NIT (IN_F / BK)      // 64 K-iterations, full K per block

typedef unsigned short u16;
typedef __attribute__((ext_vector_type(8))) short short8;
typedef __attribute__((ext_vector_type(4))) float floatx4;

__device__ __forceinline__ u16 f32_to_bf16_rne(float f) {
    uint32_t u = __builtin_bit_cast(uint32_t, f);
    uint32_t r = (u + 0x7FFFu + ((u >> 16) & 1u)) >> 16;
    return (u16)r;
}

// ---------------- prep: rowsum, lora_xA, x->bf16 (float4-vectorized) --------
__global__ __launch_bounds__(256) void prep_kernel(
    const float* __restrict__ x, const float* __restrict__ lora_A,
    u16* __restrict__ xb, float* __restrict__ srow, float* __restrict__ lxa)
{
    const int m = blockIdx.x;
    const int tid = threadIdx.x;
    const float4* xrow4 = (const float4*)(x + (size_t)m * IN_F);
    const float4* la4 = (const float4*)lora_A;
    float ssum = 0.f;
    float acc[RANK];
#pragma unroll
    for (int r = 0; r < RANK; ++r) acc[r] = 0.f;
#pragma unroll
    for (int t = 0; t < IN_F / (256 * 4); ++t) {
        int i4 = t * 256 + tid;
        float4 v = xrow4[i4];
        ssum += v.x + v.y + v.z + v.w;
        union { u16 h[4]; uint2 u2; } pk;
        pk.h[0] = f32_to_bf16_rne(v.x);
        pk.h[1] = f32_to_bf16_rne(v.y);
        pk.h[2] = f32_to_bf16_rne(v.z);
        pk.h[3] = f32_to_bf16_rne(v.w);
        *(uint2*)&xb[(size_t)m * IN_F + i4 * 4] = pk.u2;
#pragma unroll
        for (int r = 0; r < RANK; ++r) {
            float4 a = la4[r * (IN_F / 4) + i4];
            acc[r] = fmaf(v.x, a.x, fmaf(v.y, a.y, fmaf(v.z, a.z, fmaf(v.w, a.w, acc[r]))));
        }
    }
#pragma unroll
    for (int off = 32; off > 0; off >>= 1) {
        ssum += __shfl_down(ssum, off, 64);
#pragma unroll
        for (int r = 0; r < RANK; ++r) acc[r] += __shfl_down(acc[r], off, 64);
    }
    __shared__ float red[4][RANK + 1];
    int wv = tid >> 6, ln = tid & 63;
    if (ln == 0) {
        red[wv][0] = ssum;
#pragma unroll
        for (int r = 0; r < RANK; ++r) red[wv][1 + r] = acc[r];
    }
    __syncthreads();
    if (tid == 0) srow[m] = red[0][0] + red[1][0] + red[2][0] + red[3][0];
    if (tid < RANK)
        lxa[m * RANK + tid] = red[0][1 + tid] + red[1][1 + tid] + red[2][1 + tid] + red[3][1 + tid];
}

// ---------------- ternary decode: 8 x 2-bit codes -> 8 bf16 ----------------
// VERIFIED (R1/R2/R4/R5/R6): OR-based spread, no carries.
// code c: 0 -> -1 (0xBF80), 1 -> 0 (0x0000), 2 -> +1 (0x3F80)
__device__ __forceinline__ short8 decode8(uint32_t h)
{
    uint32_t selA = (h & 0xFu) | ((h & 0xF0u) << 12);
    selA = (selA | (selA << 6)) & 0x03030303u;
    uint32_t h2 = h >> 8;
    uint32_t selB = (h2 & 0xFu) | ((h2 & 0xF0u) << 12);
    selB = (selB | (selB << 6)) & 0x03030303u;
    uint32_t hiA = __builtin_amdgcn_perm(0u, 0x003F00BFu, selA);
    uint32_t loA = __builtin_amdgcn_perm(0u, 0x00800080u, selA);
    uint32_t hiB = __builtin_amdgcn_perm(0u, 0x003F00BFu, selB);
    uint32_t loB = __builtin_amdgcn_perm(0u, 0x00800080u, selB);
    union { uint32_t u[4]; short8 s; } cvt;
    cvt.u[0] = __builtin_amdgcn_perm(hiA, loA, 0x05010400u);
    cvt.u[1] = __builtin_amdgcn_perm(hiA, loA, 0x07030602u);
    cvt.u[2] = __builtin_amdgcn_perm(hiB, loB, 0x05010400u);
    cvt.u[3] = __builtin_amdgcn_perm(hiB, loB, 0x07030602u);
    return cvt.s;
}

#define WAITV6 asm volatile("s_waitcnt vmcnt(6)" ::: "memory")
#define WAITV3 asm volatile("s_waitcnt vmcnt(3)" ::: "memory")
#define WAITV0 asm volatile("s_waitcnt vmcnt(0)" ::: "memory")
#define BAR    __builtin_amdgcn_s_barrier()
#define SCHED0 __builtin_amdgcn_sched_barrier(0)

struct Frags {
    short8 af[2][2];
    uint32_t bwd[2];
};

// --- fused GEMM: 64x32 tile, 4 LDS buffers, reg-pipelined fragments ---
// R7 + fix: global_load_lds writes to (wave-uniform base + lane*16) — the
// per-lane dest is NOT honored (m104/m108). B buffer is 64 slots; lanes
// 32..63 duplicate rows 0..31 into dead slots 32..63 (never read).
__global__ __launch_bounds__(256, 4) void gemm_kernel(
    const u16* __restrict__ xb, const uint32_t* __restrict__ Tp,
    const float* __restrict__ alpha, const float* __restrict__ mu,
    const float* __restrict__ bias, const float* __restrict__ lora_B,
    const float* __restrict__ srow, const float* __restrict__ lxa,
    float* __restrict__ out)
{
    __shared__ __align__(16) u16 ldsA[4][BM * BK];       // 4 x 8 KB
    __shared__ __align__(16) uint32_t ldsB[4][256];      // 4 x 1 KB (half dead)

    const int tid = threadIdx.x;
    const int lane = tid & 63;
    const int wave = tid >> 6;
    const int wm = wave >> 1, wn = wave & 1;
    const int mb = blockIdx.y * BM;
    const int nb = blockIdx.x * BN;

    const int bshift = ((lane >> 4) & 1) * 16;

    // A-stage: 512 x 16B chunks; 2 per thread; XOR-swizzled SOURCE, linear dest
    // (dest pattern == base + lane*16 exactly, as HW requires)
    const u16* asrc[2];
    int adst[2];
#pragma unroll
    for (int j = 0; j < 2; ++j) {
        int q = j * 256 + tid;
        int row = q >> 3;            // 8 chunks per 64-elem row
        int scc = (q & 7) ^ (row & 7);
        asrc[j] = xb + (size_t)(mb + row) * IN_F + scc * 8;
        adst[j] = q * 8;             // u16 elements
    }
    // B-stage: source row nb+(lane&31); dest = lane*16B (HW-forced linear).
    const uint32_t* bsrc = Tp + (size_t)(nb + (lane & 31)) * NWORDS;
    const int bdst = lane * 4;       // u32 elements; slots 32..63 are dead dup

    // precomputed per-thread fragment offsets (compile-time indexed)
    int aoff[2][2], boff[2];
#pragma unroll
    for (int mt = 0; mt < 2; ++mt)
#pragma unroll
        for (int kk = 0; kk < 2; ++kk) {
            int r = wm * 32 + mt * 16 + (lane & 15);
            int sc = kk * 4 + (lane >> 4);
            aoff[mt][kk] = (r * 8 + (sc ^ (r & 7))) * 8;   // u16 units
        }
#pragma unroll
    for (int kk = 0; kk < 2; ++kk) {
        int row = wn * 16 + (lane & 15);
        boff[kk] = row * 4 + kk * 2 + (lane >> 5);
    }

    floatx4 acc[2] = {};

    auto stage = [&](int buf, int git) {
        const int k0 = git * BK;
#pragma unroll
        for (int j = 0; j < 2; ++j) {
            __builtin_amdgcn_global_load_lds(
                (const __attribute__((address_space(1))) void*)(asrc[j] + k0),
                (__attribute__((address_space(3))) void*)(&ldsA[buf][adst[j]]),
                16, 0, 0);
        }
        __builtin_amdgcn_global_load_lds(
            (const __attribute__((address_space(1))) void*)(bsrc + git * 4),
            (__attribute__((address_space(3))) void*)(&ldsB[buf][bdst]),
            16, 0, 0);
    };

    auto rdfrags = [&](int buf, Frags& F) {
#pragma unroll
        for (int mt = 0; mt < 2; ++mt)
#pragma unroll
            for (int kk = 0; kk < 2; ++kk)
                F.af[mt][kk] = *(const short8*)&ldsA[buf][aoff[mt][kk]];
#pragma unroll
        for (int kk = 0; kk < 2; ++kk)
            F.bwd[kk] = ldsB[buf][boff[kk]];
    };

    auto compute = [&](Frags& F) {
        __builtin_amdgcn_s_setprio(1);
#pragma unroll
        for (int kk = 0; kk < 2; ++kk) {
            short8 bf = decode8((F.bwd[kk] >> bshift) & 0xFFFFu);
#pragma unroll
            for (int mt = 0; mt < 2; ++mt)
                acc[mt] = __builtin_amdgcn_mfma_f32_16x16x32_bf16(
                    F.af[mt][kk], bf, acc[mt], 0, 0, 0);
        }
        __builtin_amdgcn_s_setprio(0);
    };

    Frags fA, fB;

    // prologue: fill 3 buffers; read frags(0)
    stage(0, 0);
    stage(1, 1);
    stage(2, 2);
    WAITV6; BAR;                 // tile 0 landed for all waves
    rdfrags(0, fA); SCHED0;

    // steady: j = 0..59, unrolled x4 (buffer index compile-time)
    for (int u = 0; u < 15; ++u) {
        const int jb = u * 4;
        stage(3, jb + 3); SCHED0; compute(fA); WAITV6; BAR; rdfrags(1, fB); SCHED0;
        stage(0, jb + 4); SCHED0; compute(fB); WAITV6; BAR; rdfrags(2, fA); SCHED0;
        stage(1, jb + 5); SCHED0; compute(fA); WAITV6; BAR; rdfrags(3, fB); SCHED0;
        stage(2, jb + 6); SCHED0; compute(fB); WAITV6; BAR; rdfrags(0, fA); SCHED0;
    }
    // j = 60 (stages last tile 63), then drain 61/62/63
    stage(3, 63); SCHED0; compute(fA); WAITV6; BAR; rdfrags(1, fB); SCHED0;
    compute(fB); WAITV3; BAR; rdfrags(2, fA); SCHED0;   // j = 61
    compute(fA); WAITV0; BAR; rdfrags(3, fB); SCHED0;   // j = 62
    compute(fB);                                        // j = 63

    // ---- fused epilogue: out = alpha*acc + mu*rowsum + 2*lora + bias ----
    const int o0 = nb + wn * 16 + (lane & 15);
    const int m0 = mb + wm * 32 + ((lane >> 4) * 4);

    float al = alpha[o0];
    float muv = mu[o0];
    float bi = bias[o0];
    float Brow[RANK];
    const float4* b4 = (const float4*)(lora_B + (size_t)o0 * RANK);
#pragma unroll
    for (int r4 = 0; r4 < RANK / 4; ++r4) {
        float4 v = b4[r4];
        Brow[r4 * 4 + 0] = v.x; Brow[r4 * 4 + 1] = v.y;
        Brow[r4 * 4 + 2] = v.z; Brow[r4 * 4 + 3] = v.w;
    }
#pragma unroll
    for (int mt = 0; mt < 2; ++mt) {
#pragma unroll
        for (int rg = 0; rg < 4; ++rg) {
            int m = m0 + mt * 16 + rg;
            float sm = srow[m];
            float lx[RANK];
            const float4* l4 = (const float4*)(lxa + (size_t)m * RANK);
#pragma unroll
            for (int r4 = 0; r4 < RANK / 4; ++r4) {
                float4 v = l4[r4];
                lx[r4 * 4 + 0] = v.x; lx[r4 * 4 + 1] = v.y;
                lx[r4 * 4 + 2] = v.z; lx[r4 * 4 + 3] = v.w;
            }
            float lora = 0.f;
#pragma unroll
            for (int r = 0; r < RANK; ++r) lora = fmaf(lx[r], Brow[r], lora);
            out[(size_t)m * OUT_F + o0] =
                al * acc[mt][rg] + muv * sm + 2.0f * lora + bi;
        }
    }
}

extern "C" void kernel_launch(void* const* d_in, const int* in_sizes, int n_in,
                              void* d_out, int out_size, void* d_ws, size_t ws_size,
                              hipStream_t stream)
{
    const float* x = (const float*)d_in[0];
    const uint32_t* Tp = (const uint32_t*)d_in[1];
    const float* alpha = (const float*)d_in[2];
    const float* mu = (const float*)d_in[3];
    const float* bias = (const float*)d_in[4];
    const float* lora_A = (const float*)d_in[5];
    const float* lora_B = (const float*)d_in[6];
    float* out = (float*)d_out;

    u16* xb = (u16*)d_ws;
    float* srow = (float*)((char*)d_ws + (size_t)M_ROWS * IN_F * 2);
    float* lxa = (float*)((char*)d_ws + (size_t)M_ROWS * IN_F * 2 + 4096);

    prep_kernel<<<dim3(M_ROWS), dim3(256), 0, stream>>>(x, lora_A, xb, srow, lxa);
    gemm_kernel<<<dim3(OUT_F / BN, M_ROWS / BM), dim3(256), 0, stream>>>(
        xb, Tp, alpha, mu, bias, lora_B, srow, lxa, out);
}